// Round 8
// baseline (1634.336 us; speedup 1.0000x reference)
//
#include <hip/hip_runtime.h>

// ---------------------------------------------------------------------------
// TLSTM  (B=256, T=256, D=256, H=512)
// Persistent-scan, R7 = R6 exchange protocol (proven) + software-pipelined
// x-path. At step t:
//   A: issue h/c(t) coherent loads; issue x(t+2) + tim(t) loads in the shadow;
//      vmcnt(0); tag-validate + retry (R6 verbatim).
//   B: commit h/c to LDS.   bar1
//   C: w0: Zi,Zf U-GEMM; w1: Zo,Zc; w2: decomp m0+m1; w3: x-proj(t+1) from
//      X (staged at t-1) into Z2[(t+1)&1].   bar2
//   D: elementwise reads U-tiles + decomp + Z2[t&1]; publishes tagged u64.
//   E: stage X(t+2) from regs.   bar3
// The recurrence-critical chain is now validate -> commit -> U-MFMA ->
// elementwise -> publish; all x work rides on wave 3 / phase E.
// Prologue: stage X(0), w3 x-proj(0)->Z2[0], stage X(1).
// ---------------------------------------------------------------------------

#define T_STEPS 256
#define BATCH   256
#define DIN     256
#define HID     512

typedef __attribute__((ext_vector_type(8))) __bf16 bf16x8;
typedef __attribute__((ext_vector_type(4))) float  f32x4;

#define MFMA(a,b,c) __builtin_amdgcn_mfma_f32_16x16x32_bf16((a),(b),(c),0,0,0)

// LDS layout (byte offsets).
#define H_S     0            // 32 x 1040B (520 bf16)
#define C_S     33280        // 32 x 1040B
#define X_S     66560        // 32 x 528B  (264 bf16)
#define WIN_S   83456        // 4 x 16 x 528B
#define Z_S     117248       // 10 tiles x 16x17 f32 (U: 0..7, decomp: 8,9)
#define Z2_S    128128       // 2 x 8 tiles x 16x17 f32 (x-proj, parity)
#define LDS_SZ  145536
#define HSTR    1040
#define XSTR    528
#define ZROW    17

struct ScanP {
  const float *x, *tim;
  const float *Wi_w,*Wi_b,*Ui_w,*Ui_b,*bi;
  const float *Wf_w,*Wf_b,*Uf_w,*Uf_b,*bf_;
  const float *Wo_w,*Wo_b,*Uo_w,*Uo_b,*bo;
  const float *Wc_w,*Wc_b,*Uc_w,*Uc_b,*bc;
  const float *Wd_w,*b_dec;
  unsigned long long *hc_buf;      // [2][256 rows][256 col-pairs] u64
  float *h_final;                  // [256][512] fp32
  unsigned int *flags;             // [8][32] (kept from R3 layout; unused)
};

__device__ __forceinline__ float fsigm(float z){ return 1.f/(1.f + __expf(-z)); }
__device__ __forceinline__ float ftanh(float z){
  float e = __expf(-2.f*fabsf(z));
  float t = (1.f - e)/(1.f + e);
  return z < 0.f ? -t : t;
}

// device-coherent via MALL (bypass non-coherent L1+L2) — R3/R6-proven path
__device__ __forceinline__ uint4 cld16(const void* p){
  uint4 r;
  asm volatile("global_load_dwordx4 %0, %1, off sc0 sc1"
               : "=v"(r) : "v"(p) : "memory");
  return r;
}
__device__ __forceinline__ void cst8(void* p, unsigned long long v){
  asm volatile("global_store_dwordx2 %0, %1, off sc0 sc1"
               :: "v"(p), "v"(v) : "memory");
}

__device__ __forceinline__ bf16x8 wfrag8(const float* p){
  const float4* p4 = (const float4*)p;
  float4 a = p4[0], b = p4[1];
  bf16x8 r = { (__bf16)a.x,(__bf16)a.y,(__bf16)a.z,(__bf16)a.w,
               (__bf16)b.x,(__bf16)b.y,(__bf16)b.z,(__bf16)b.w };
  return r;
}
__device__ __forceinline__ void zstore(char* L, int tile, int lane, f32x4 v){
  float* p = (float*)(L + Z_S) + tile*(16*ZROW) + ((lane>>4)*4)*ZROW + (lane&15);
  p[0]=v[0]; p[ZROW]=v[1]; p[2*ZROW]=v[2]; p[3*ZROW]=v[3];
}
__device__ __forceinline__ float zread(const char* L, int tile, int r, int c){
  return ((const float*)(L + Z_S))[tile*(16*ZROW) + r*ZROW + c];
}
__device__ __forceinline__ void z2store(char* L, int p, int tile, int lane, f32x4 v){
  float* q = (float*)(L + Z2_S) + (p*8 + tile)*(16*ZROW) + ((lane>>4)*4)*ZROW + (lane&15);
  q[0]=v[0]; q[ZROW]=v[1]; q[2*ZROW]=v[2]; q[3*ZROW]=v[3];
}
__device__ __forceinline__ float z2read(const char* L, int p, int tile, int r, int c){
  return ((const float*)(L + Z2_S))[(p*8 + tile)*(16*ZROW) + r*ZROW + c];
}

// stage x fp32 regs -> bf16 X tile (staging map: srow=tid>>3, sseg=tid&7)
__device__ __forceinline__ void stageX(char* L, int srow, int sseg, const float4* xv){
  char* dst = L + X_S + srow * XSTR + sseg * 64;
#pragma unroll
  for (int j = 0; j < 4; j++){
    float4 a = xv[2*j], b = xv[2*j+1];
    bf16x8 o = { (__bf16)a.x,(__bf16)a.y,(__bf16)a.z,(__bf16)a.w,
                 (__bf16)b.x,(__bf16)b.y,(__bf16)b.z,(__bf16)b.w };
    *(bf16x8*)(dst + j*16) = o;
  }
}

// wave3: x-projections (4 gates x 2 M-tiles) from X -> Z2[p]
__device__ __forceinline__ void xproj_w3(char* L, int lane, int p){
  const int lo = lane & 15, hi = lane >> 4;
#pragma unroll
  for (int m = 0; m < 2; m++){
    f32x4 xi = {0.f,0.f,0.f,0.f}, xf = xi, xo = xi, xcg = xi;
#pragma unroll
    for (int q = 0; q < 8; q++){
      bf16x8 a  = *(const bf16x8*)(L + X_S   + (m*16 + lo) * XSTR + q*64 + hi*16);
      bf16x8 w0 = *(const bf16x8*)(L + WIN_S + (0*16 + lo) * XSTR + q*64 + hi*16);
      bf16x8 w1 = *(const bf16x8*)(L + WIN_S + (1*16 + lo) * XSTR + q*64 + hi*16);
      bf16x8 w2 = *(const bf16x8*)(L + WIN_S + (2*16 + lo) * XSTR + q*64 + hi*16);
      bf16x8 w3 = *(const bf16x8*)(L + WIN_S + (3*16 + lo) * XSTR + q*64 + hi*16);
      xi  = MFMA(a, w0, xi);  xf  = MFMA(a, w1, xf);
      xo  = MFMA(a, w2, xo);  xcg = MFMA(a, w3, xcg);
    }
    z2store(L, p, 4*m+0, lane, xi);  z2store(L, p, 4*m+1, lane, xf);
    z2store(L, p, 4*m+2, lane, xo);  z2store(L, p, 4*m+3, lane, xcg);
  }
}

__global__ void __launch_bounds__(256, 1) tlstm_scan(ScanP P)
{
  __shared__ __align__(16) char L[LDS_SZ];
  const int tid  = threadIdx.x;
  const int bid  = blockIdx.x;
  const int g    = bid & 7;          // row group
  const int cs   = bid >> 3;         // 0..31
  const int rbase = g * 32;
  const int cbase = cs * 16;
  const int wave = tid >> 6, lane = tid & 63, lo = lane & 15, hi = lane >> 4;

  // ---- one-time: Win slices (4 gates x 16 cols x 256) fp32 -> bf16 -> LDS
  {
    const float* Wg = (tid < 64) ? P.Wi_w : (tid < 128) ? P.Wf_w
                    : (tid < 192) ? P.Wo_w : P.Wc_w;
    int wr = (tid >> 2) & 15, q = tid & 3;
    const float4* src = (const float4*)(Wg + (size_t)(cbase + wr) * DIN + q * 64);
    char* dst = L + WIN_S + (size_t)((tid >> 6) * 16 + wr) * XSTR + q * 128;
#pragma unroll
    for (int j = 0; j < 8; j++){
      float4 a = src[2*j], b = src[2*j+1];
      bf16x8 o = { (__bf16)a.x,(__bf16)a.y,(__bf16)a.z,(__bf16)a.w,
                   (__bf16)b.x,(__bf16)b.y,(__bf16)b.z,(__bf16)b.w };
      *(bf16x8*)(dst + j*16) = o;
    }
  }

  // ---- one-time: U/Wd B-fragments -> registers (loop-invariant)
  bf16x8 bP[16], bQ[16];
  {
    const float* Pw = (wave == 0) ? P.Ui_w : (wave == 1) ? P.Uo_w : P.Wd_w;
#pragma unroll
    for (int kc = 0; kc < 16; kc++)
      bP[kc] = wfrag8(Pw + (size_t)(cbase + lo) * HID + kc * 32 + hi * 8);
    if (wave < 2){
      const float* Qw = (wave == 0) ? P.Uf_w : P.Uc_w;
#pragma unroll
      for (int kc = 0; kc < 16; kc++)
        bQ[kc] = wfrag8(Qw + (size_t)(cbase + lo) * HID + kc * 32 + hi * 8);
    }
  }

  // ---- per-thread elementwise ownership
  const int erow = tid >> 3;
  const int ecp  = (tid & 7) * 2;
  float bias_i[2], bias_f[2], bias_o[2], bias_c[2], bias_d[2], cr[2];
#pragma unroll
  for (int e = 0; e < 2; e++){
    int c = cbase + ecp + e;
    bias_i[e] = P.Wi_b[c] + P.bi[c]  + P.Ui_b[c];
    bias_f[e] = P.Wf_b[c] + P.bf_[c] + P.Uf_b[c];
    bias_o[e] = P.Wo_b[c] + P.bo[c]  + P.Uo_b[c];
    bias_c[e] = P.Wc_b[c] + P.bc[c]  + P.Uc_b[c];
    bias_d[e] = P.b_dec[c];
    cr[e] = 0.f;
  }

  const int srow = tid >> 3, sseg = tid & 7;   // x staging map

  // ---- prologue: X(0) staged, x-proj(0) -> Z2[0], X(1) staged
  float4 xv[8];
  {
    const float4* xs = (const float4*)(P.x + ((size_t)(rbase + srow) * T_STEPS + 0) * DIN + sseg * 32);
#pragma unroll
    for (int j = 0; j < 8; j++) xv[j] = xs[j];
    stageX(L, srow, sseg, xv);
  }
  __syncthreads();
  if (wave == 3) xproj_w3(L, lane, 0);
  {
    const float4* xs = (const float4*)(P.x + ((size_t)(rbase + srow) * T_STEPS + 1) * DIN + sseg * 32);
#pragma unroll
    for (int j = 0; j < 8; j++) xv[j] = xs[j];
  }
  __syncthreads();            // x-proj(0) done -> X reusable
  stageX(L, srow, sseg, xv);  // X := x(1)
  __syncthreads();

#pragma unroll 1
  for (int t = 0; t < T_STEPS; ++t){
    const int rp = t & 1;
    const char* hcprev = (const char*)(P.hc_buf + (size_t)rp * BATCH * 256);
    char* hcnext = (char*)(P.hc_buf + (size_t)(rp ^ 1) * BATCH * 256);

    // ---- A: issue h/c coherent loads (16 x dwordx4, in flight)
    uint4 gr[16];
    const char* src = hcprev + (size_t)(rbase + wave * 8) * 2048;
#pragma unroll
    for (int j = 0; j < 16; j++){
      int row = j >> 1;                       // within this wave's 8 rows
      int gg  = (j & 1) * 64 + lane;          // 16B granule within row
      gr[j] = cld16(src + (size_t)row * 2048 + (size_t)gg * 16);
    }
    // fill the load shadow: x(t+2) + tim(t) (plain cached loads)
    if (t < T_STEPS - 2){
      const float4* xs = (const float4*)(P.x + ((size_t)(rbase + srow) * T_STEPS + (t + 2)) * DIN + sseg * 32);
#pragma unroll
      for (int j = 0; j < 8; j++) xv[j] = xs[j];
    }
    float tv = P.tim[(size_t)(rbase + erow) * T_STEPS + t];

    asm volatile("s_waitcnt vmcnt(0)" ::: "memory");
    __builtin_amdgcn_sched_barrier(0);

    // ---- validate tags (R6 verbatim); retry until fresh (guarded)
    {
      const unsigned int expv = (unsigned int)(t & 1)
                              | ((unsigned int)((t >> 1) & 1) << 16);
      unsigned int bad = 0;
#pragma unroll
      for (int j = 0; j < 16; j++)
        bad |= ((gr[j].x ^ expv) | (gr[j].y ^ expv)
              | (gr[j].z ^ expv) | (gr[j].w ^ expv)) & 0x00010001u;
      int guard = 0;
      while (__any((int)bad) && ++guard < 65536){
#pragma unroll
        for (int j = 0; j < 16; j++){
          int row = j >> 1;
          int gg  = (j & 1) * 64 + lane;
          gr[j] = cld16(src + (size_t)row * 2048 + (size_t)gg * 16);
        }
        asm volatile("s_waitcnt vmcnt(0)" ::: "memory");
        __builtin_amdgcn_sched_barrier(0);
        bad = 0;
#pragma unroll
        for (int j = 0; j < 16; j++)
          bad |= ((gr[j].x ^ expv) | (gr[j].y ^ expv)
                | (gr[j].z ^ expv) | (gr[j].w ^ expv)) & 0x00010001u;
      }
    }

    // ---- B: commit h/c to LDS. gr = [h01,c01,h23,c23] -> h {x,z}, c {y,w}
    {
#pragma unroll
      for (int j = 0; j < 16; j++){
        int row = wave * 8 + (j >> 1);
        int gg  = (j & 1) * 64 + lane;
        *(uint2*)(L + H_S + row * HSTR + gg * 8) = uint2{gr[j].x, gr[j].z};
        *(uint2*)(L + C_S + row * HSTR + gg * 8) = uint2{gr[j].y, gr[j].w};
      }
    }
    __syncthreads();

    // ---- C: MFMA phase
    if (wave < 2){
      // wave0: Zi,Zf (U-parts, both M-tiles); wave1: Zo,Zc
      f32x4 z0 = {0.f,0.f,0.f,0.f}, z1 = z0, z2 = z0, z3 = z0;
#pragma unroll
      for (int kc = 0; kc < 16; kc++){
        bf16x8 a0 = *(const bf16x8*)(L + H_S + lo * HSTR        + kc*64 + hi*16);
        bf16x8 a1 = *(const bf16x8*)(L + H_S + (16 + lo) * HSTR + kc*64 + hi*16);
        z0 = MFMA(a0, bP[kc], z0);
        z1 = MFMA(a1, bP[kc], z1);
        z2 = MFMA(a0, bQ[kc], z2);
        z3 = MFMA(a1, bQ[kc], z3);
      }
      int tb = wave * 4;   // tiles {0..3} = Zi m0,m1, Zf m0,m1 ; {4..7} = Zo,Zc
      zstore(L, tb+0, lane, z0); zstore(L, tb+1, lane, z1);
      zstore(L, tb+2, lane, z2); zstore(L, tb+3, lane, z3);
    } else if (wave == 2){
      // wave2: decomp both M-tiles (bP = Wd)
      f32x4 zd0 = {0.f,0.f,0.f,0.f}, zd1 = zd0;
#pragma unroll
      for (int kc = 0; kc < 16; kc++){
        bf16x8 a0 = *(const bf16x8*)(L + C_S + lo * HSTR        + kc*64 + hi*16);
        bf16x8 a1 = *(const bf16x8*)(L + C_S + (16 + lo) * HSTR + kc*64 + hi*16);
        zd0 = MFMA(a0, bP[kc], zd0);
        zd1 = MFMA(a1, bP[kc], zd1);
      }
      zstore(L, 8, lane, zd0); zstore(L, 9, lane, zd1);
    } else {
      // wave3: x-projections for step t+1 (from X staged at step t-1)
      if (t + 1 < T_STEPS) xproj_w3(L, lane, (t + 1) & 1);
    }
    __syncthreads();

    // ---- D: elementwise gate math (fp32); publish tagged u64
    {
      const int m = erow >> 4, r16 = erow & 15;
      const int p2 = t & 1;
      float Tmap = 1.f / __logf(tv + 2.7183f);
      unsigned int hpk = 0, cpk = 0;
      float hv2[2];
#pragma unroll
      for (int e = 0; e < 2; e++){
        int col = ecp + e;
        float zi = zread(L, 0*2+m, r16, col) + z2read(L, p2, 4*m+0, r16, col) + bias_i[e];
        float zf = zread(L, 1*2+m, r16, col) + z2read(L, p2, 4*m+1, r16, col) + bias_f[e];
        float zo = zread(L, 2*2+m, r16, col) + z2read(L, p2, 4*m+2, r16, col) + bias_o[e];
        float zc = zread(L, 3*2+m, r16, col) + z2read(L, p2, 4*m+3, r16, col) + bias_c[e];
        float zdv = zread(L, 8+m, r16, col) + bias_d[e];
        float cst = ftanh(zdv);
        float c1  = cr[e] - cst + Tmap * cst;
        float ig = fsigm(zi), fg = fsigm(zf), og = fsigm(zo);
        float ch = ftanh(zc);
        float c2 = fg * c1 + ig * ch;
        float hv_ = og * ftanh(c2);
        cr[e] = c2; hv2[e] = hv_;
        hpk |= (unsigned int)__builtin_bit_cast(unsigned short, (__bf16)hv_) << (16*e);
        cpk |= (unsigned int)__builtin_bit_cast(unsigned short, (__bf16)c2) << (16*e);
      }
      if (t < T_STEPS - 1){
        const unsigned int wtag  = (unsigned int)((t + 1) & 3);
        const unsigned int tmask = (wtag & 1u) | ((wtag >> 1) << 16);
        hpk = (hpk & 0xFFFEFFFEu) | tmask;   // full tag in both bf16 LSBs
        cpk = (cpk & 0xFFFEFFFEu) | tmask;
        size_t off = ((size_t)(rbase + erow) * 256 + (cbase >> 1) + (tid & 7)) * 8;
        cst8(hcnext + off,
             (unsigned long long)hpk | ((unsigned long long)cpk << 32));
      } else {
        size_t off = (size_t)(rbase + erow) * HID + cbase + ecp;
        P.h_final[off]     = hv2[0];
        P.h_final[off + 1] = hv2[1];
      }
    }

    // ---- E: stage X(t+2) for next step's wave3 x-proj
    if (t < T_STEPS - 2) stageX(L, srow, sseg, xv);
    __syncthreads();
  }
}

// ---------------- head: out = relu(hT @ fc_w^T + fc_b) @ cls_w^T + cls_b ----
__global__ void __launch_bounds__(256) tlstm_head(const float* __restrict__ hfin,
    const float* __restrict__ fc_w, const float* __restrict__ fc_b,
    const float* __restrict__ cls_w, const float* __restrict__ cls_b,
    float* __restrict__ out)
{
  __shared__ float hrow[512];
  __shared__ float fcv[256];
  const int b = blockIdx.x, tid = threadIdx.x;
  ((float2*)hrow)[tid] = ((const float2*)(hfin + (size_t)b * 512))[tid];
  __syncthreads();
  {
    const float4* w4 = (const float4*)(fc_w + (size_t)tid * 512);
    const float4* h4 = (const float4*)hrow;
    float acc = fc_b[tid];
#pragma unroll 4
    for (int k = 0; k < 128; k++){
      float4 w = w4[k], h = h4[k];
      acc += w.x*h.x + w.y*h.y + w.z*h.z + w.w*h.w;
    }
    fcv[tid] = fmaxf(acc, 0.f);
  }
  __syncthreads();
  const int wave = tid >> 6, lane = tid & 63;
  if (wave < 2){
    const float* cw = cls_w + wave * 256;
    float s = 0.f;
#pragma unroll
    for (int j = lane; j < 256; j += 64) s += fcv[j] * cw[j];
#pragma unroll
    for (int off = 32; off > 0; off >>= 1) s += __shfl_down(s, off, 64);
    if (lane == 0) out[b * 2 + wave] = s + cls_b[wave];
  }
}

// ---------------------------------------------------------------------------
extern "C" void kernel_launch(void* const* d_in, const int* in_sizes, int n_in,
                              void* d_out, int out_size, void* d_ws, size_t ws_size,
                              hipStream_t stream)
{
  (void)in_sizes; (void)n_in; (void)out_size; (void)ws_size;

  ScanP P;
  P.x    = (const float*)d_in[0];
  P.tim  = (const float*)d_in[1];
  P.Wi_w = (const float*)d_in[2];  P.Wi_b = (const float*)d_in[3];
  P.Ui_w = (const float*)d_in[4];  P.Ui_b = (const float*)d_in[5];  P.bi  = (const float*)d_in[6];
  P.Wf_w = (const float*)d_in[7];  P.Wf_b = (const float*)d_in[8];
  P.Uf_w = (const float*)d_in[9];  P.Uf_b = (const float*)d_in[10]; P.bf_ = (const float*)d_in[11];
  P.Wo_w = (const float*)d_in[12]; P.Wo_b = (const float*)d_in[13];
  P.Uo_w = (const float*)d_in[14]; P.Uo_b = (const float*)d_in[15]; P.bo  = (const float*)d_in[16];
  P.Wc_w = (const float*)d_in[17]; P.Wc_b = (const float*)d_in[18];
  P.Uc_w = (const float*)d_in[19]; P.Uc_b = (const float*)d_in[20]; P.bc  = (const float*)d_in[21];
  P.Wd_w = (const float*)d_in[22]; P.b_dec = (const float*)d_in[23];
  const float* fc_w  = (const float*)d_in[24];
  const float* fc_b  = (const float*)d_in[25];
  const float* cls_w = (const float*)d_in[26];
  const float* cls_b = (const float*)d_in[27];

  // workspace layout (identical to R3/R6): [hc_buf 1M][flags 1K][h_final 512K]
  unsigned long long* hc_buf = (unsigned long long*)d_ws;        // 2*256*256 u64
  unsigned int* flags = (unsigned int*)(hc_buf + 2 * BATCH * 256);
  float* h_final = (float*)((char*)flags + 1024);                // 256*512 f32
  P.hc_buf = hc_buf; P.h_final = h_final; P.flags = flags;

  const size_t zero_bytes = (size_t)2 * BATCH * 256 * 8 + 1024;  // hc + flags
  hipMemsetAsync(d_ws, 0, zero_bytes, stream);

  hipLaunchKernelGGL(tlstm_scan, dim3(256), dim3(256), 0, stream, P);
  hipLaunchKernelGGL(tlstm_head, dim3(256), dim3(256), 0, stream,
                     h_final, fc_w, fc_b, cls_w, cls_b, (float*)d_out);
}

// Round 9
// 1164.880 us; speedup vs baseline: 1.4030x; 1.4030x over previous
//
#include <hip/hip_runtime.h>

// ---------------------------------------------------------------------------
// TLSTM  (B=256, T=256, D=256, H=512)
// Persistent-scan, R8 = R6 (proven, 1158us) + ONE delta: SELECTIVE retry.
//   R6/R7 retried by reloading ALL 16 exchanged u64s per round (16KB/wave)
//   -> retry amplification of MALL traffic was the hypothesized dominant
//   term (R7's +48MB FETCH = retry spill). R8 keeps a per-lane 16-bit stale
//   mask and reloads ONLY stale u64s on stale lanes (exec-masked), then
//   revalidates only those. Happy path identical; guard preserved (no-hang).
//   Everything else — exchange protocol (tagged u64, full 2-bit tag in every
//   dword), LDS map, staging, MFMA split, elementwise, ws layout — is R6
//   verbatim.
// ---------------------------------------------------------------------------

#define T_STEPS 256
#define BATCH   256
#define DIN     256
#define HID     512

typedef __attribute__((ext_vector_type(8))) __bf16 bf16x8;
typedef __attribute__((ext_vector_type(4))) float  f32x4;

#define MFMA(a,b,c) __builtin_amdgcn_mfma_f32_16x16x32_bf16((a),(b),(c),0,0,0)

// LDS layout (byte offsets).
#define H_S     0            // 32 x 1040B (520 bf16)
#define C_S     33280        // 32 x 1040B
#define X_S     66560        // 32 x 528B  (264 bf16)
#define WIN_S   83456        // 4 x 16 x 528B
#define Z_S     117248       // 18 tiles x 16x17 f32
#define LDS_SZ  136832
#define HSTR    1040
#define XSTR    528
#define ZROW    17

struct ScanP {
  const float *x, *tim;
  const float *Wi_w,*Wi_b,*Ui_w,*Ui_b,*bi;
  const float *Wf_w,*Wf_b,*Uf_w,*Uf_b,*bf_;
  const float *Wo_w,*Wo_b,*Uo_w,*Uo_b,*bo;
  const float *Wc_w,*Wc_b,*Uc_w,*Uc_b,*bc;
  const float *Wd_w,*b_dec;
  unsigned long long *hc_buf;      // [2][256 rows][256 col-pairs] u64
  float *h_final;                  // [256][512] fp32
  unsigned int *flags;             // [8][32] (kept from R3 layout; unused)
};

__device__ __forceinline__ float fsigm(float z){ return 1.f/(1.f + __expf(-z)); }
__device__ __forceinline__ float ftanh(float z){
  float e = __expf(-2.f*fabsf(z));
  float t = (1.f - e)/(1.f + e);
  return z < 0.f ? -t : t;
}

// device-coherent via MALL (bypass non-coherent L1+L2) — R3/R6-proven path
__device__ __forceinline__ uint4 cld16(const void* p){
  uint4 r;
  asm volatile("global_load_dwordx4 %0, %1, off sc0 sc1"
               : "=v"(r) : "v"(p) : "memory");
  return r;
}
__device__ __forceinline__ void cst8(void* p, unsigned long long v){
  asm volatile("global_store_dwordx2 %0, %1, off sc0 sc1"
               :: "v"(p), "v"(v) : "memory");
}

__device__ __forceinline__ bf16x8 wfrag8(const float* p){
  const float4* p4 = (const float4*)p;
  float4 a = p4[0], b = p4[1];
  bf16x8 r = { (__bf16)a.x,(__bf16)a.y,(__bf16)a.z,(__bf16)a.w,
               (__bf16)b.x,(__bf16)b.y,(__bf16)b.z,(__bf16)b.w };
  return r;
}
__device__ __forceinline__ void zstore(char* L, int tile, int lane, f32x4 v){
  float* p = (float*)(L + Z_S) + tile*(16*ZROW) + ((lane>>4)*4)*ZROW + (lane&15);
  p[0]=v[0]; p[ZROW]=v[1]; p[2*ZROW]=v[2]; p[3*ZROW]=v[3];
}
__device__ __forceinline__ float zread(const char* L, int tile, int r, int c){
  return ((const float*)(L + Z_S))[tile*(16*ZROW) + r*ZROW + c];
}

// Z tile ids: gate g U-part = g*2+m ; x-part = 8+4*m+g ; decomp = 16+m
__global__ void __launch_bounds__(256, 1) tlstm_scan(ScanP P)
{
  __shared__ __align__(16) char L[LDS_SZ];
  const int tid  = threadIdx.x;
  const int bid  = blockIdx.x;
  const int g    = bid & 7;          // row group
  const int cs   = bid >> 3;         // 0..31
  const int rbase = g * 32;
  const int cbase = cs * 16;
  const int wave = tid >> 6, lane = tid & 63, lo = lane & 15, hi = lane >> 4;

  // ---- one-time: Win slices (4 gates x 16 cols x 256) fp32 -> bf16 -> LDS
  {
    const float* Wg = (tid < 64) ? P.Wi_w : (tid < 128) ? P.Wf_w
                    : (tid < 192) ? P.Wo_w : P.Wc_w;
    int wr = (tid >> 2) & 15, q = tid & 3;
    const float4* src = (const float4*)(Wg + (size_t)(cbase + wr) * DIN + q * 64);
    char* dst = L + WIN_S + (size_t)((tid >> 6) * 16 + wr) * XSTR + q * 128;
#pragma unroll
    for (int j = 0; j < 8; j++){
      float4 a = src[2*j], b = src[2*j+1];
      bf16x8 o = { (__bf16)a.x,(__bf16)a.y,(__bf16)a.z,(__bf16)a.w,
                   (__bf16)b.x,(__bf16)b.y,(__bf16)b.z,(__bf16)b.w };
      *(bf16x8*)(dst + j*16) = o;
    }
  }

  // ---- one-time: U/Wd B-fragments -> registers (loop-invariant)
  bf16x8 bP[16], bQ[16];
  {
    const float* Pw = (wave == 0) ? P.Ui_w : (wave == 1) ? P.Uo_w : P.Wd_w;
#pragma unroll
    for (int kc = 0; kc < 16; kc++)
      bP[kc] = wfrag8(Pw + (size_t)(cbase + lo) * HID + kc * 32 + hi * 8);
    if (wave < 2){
      const float* Qw = (wave == 0) ? P.Uf_w : P.Uc_w;
#pragma unroll
      for (int kc = 0; kc < 16; kc++)
        bQ[kc] = wfrag8(Qw + (size_t)(cbase + lo) * HID + kc * 32 + hi * 8);
    }
  }

  // ---- per-thread elementwise ownership
  const int erow = tid >> 3;
  const int ecp  = (tid & 7) * 2;
  float bias_i[2], bias_f[2], bias_o[2], bias_c[2], bias_d[2], cr[2];
#pragma unroll
  for (int e = 0; e < 2; e++){
    int c = cbase + ecp + e;
    bias_i[e] = P.Wi_b[c] + P.bi[c]  + P.Ui_b[c];
    bias_f[e] = P.Wf_b[c] + P.bf_[c] + P.Uf_b[c];
    bias_o[e] = P.Wo_b[c] + P.bo[c]  + P.Uo_b[c];
    bias_c[e] = P.Wc_b[c] + P.bc[c]  + P.Uc_b[c];
    bias_d[e] = P.b_dec[c];
    cr[e] = 0.f;
  }

  const int srow = tid >> 3, sseg = tid & 7;   // x staging map

#pragma unroll 1
  for (int t = 0; t < T_STEPS; ++t){
    const int rp = t & 1;
    const char* hcprev = (const char*)(P.hc_buf + (size_t)rp * BATCH * 256);
    char* hcnext = (char*)(P.hc_buf + (size_t)(rp ^ 1) * BATCH * 256);

    // x slice + tim (independent of peers): issue early
    const float4* xsrc = (const float4*)(P.x + ((size_t)(rbase + srow) * T_STEPS + t) * DIN + sseg * 32);
    float4 xv[8];
#pragma unroll
    for (int j = 0; j < 8; j++) xv[j] = xsrc[j];
    float tv = P.tim[(size_t)(rbase + erow) * T_STEPS + t];

    __syncthreads();      // old LDS uses finished -> safe to restage

    // ---- issue all h/c coherent loads (16 x dwordx4 per thread, in flight)
    uint4 gr[16];
    const char* src = hcprev + (size_t)(rbase + wave * 8) * 2048;
#pragma unroll
    for (int j = 0; j < 16; j++){
      int row = j >> 1;                       // within this wave's 8 rows
      int gg  = (j & 1) * 64 + lane;          // 16B granule within row
      gr[j] = cld16(src + (size_t)row * 2048 + (size_t)gg * 16);
    }

    // ---- stage x (fp32 -> bf16) — fills the h/c load shadow
    {
      char* dst = L + X_S + srow * XSTR + sseg * 64;
#pragma unroll
      for (int j = 0; j < 4; j++){
        float4 a = xv[2*j], b = xv[2*j+1];
        bf16x8 o = { (__bf16)a.x,(__bf16)a.y,(__bf16)a.z,(__bf16)a.w,
                     (__bf16)b.x,(__bf16)b.y,(__bf16)b.z,(__bf16)b.w };
        *(bf16x8*)(dst + j*16) = o;
      }
    }

    asm volatile("s_waitcnt vmcnt(0)" ::: "memory");
    __builtin_amdgcn_sched_barrier(0);

    // ---- validate tags; SELECTIVE retry: reload only stale u64s on stale
    //      lanes (exec-masked). Guarded: no-hang by construction.
    {
      const unsigned int expv = (unsigned int)(t & 1)
                              | ((unsigned int)((t >> 1) & 1) << 16);
      unsigned int stale = 0;
#pragma unroll
      for (int j = 0; j < 16; j++){
        unsigned int bad = ((gr[j].x ^ expv) | (gr[j].y ^ expv)
                          | (gr[j].z ^ expv) | (gr[j].w ^ expv)) & 0x00010001u;
        stale |= (bad ? 1u : 0u) << j;
      }
      int guard = 0;
      while (__any((int)stale) && ++guard < 65536){
#pragma unroll
        for (int j = 0; j < 16; j++){
          if (stale & (1u << j)){
            int row = j >> 1;
            int gg  = (j & 1) * 64 + lane;
            gr[j] = cld16(src + (size_t)row * 2048 + (size_t)gg * 16);
          }
        }
        asm volatile("s_waitcnt vmcnt(0)" ::: "memory");
        __builtin_amdgcn_sched_barrier(0);
        unsigned int ns = 0;
#pragma unroll
        for (int j = 0; j < 16; j++){
          if (stale & (1u << j)){
            unsigned int bad = ((gr[j].x ^ expv) | (gr[j].y ^ expv)
                              | (gr[j].z ^ expv) | (gr[j].w ^ expv)) & 0x00010001u;
            ns |= (bad ? 1u : 0u) << j;
          }
        }
        stale = ns;
      }
    }

    // ---- commit h/c to LDS. granule gg covers cols 4gg..4gg+3:
    //      gr = [h01, c01, h23, c23] -> h u64 {x,z}, c u64 {y,w}
    {
#pragma unroll
      for (int j = 0; j < 16; j++){
        int row = wave * 8 + (j >> 1);
        int gg  = (j & 1) * 64 + lane;
        *(uint2*)(L + H_S + row * HSTR + gg * 8) = uint2{gr[j].x, gr[j].z};
        *(uint2*)(L + C_S + row * HSTR + gg * 8) = uint2{gr[j].y, gr[j].w};
      }
    }
    __syncthreads();

    // ---- MFMA phase
    if (wave < 2){
      // wave0: Zi,Zf (U-parts, both M-tiles); wave1: Zo,Zc
      f32x4 z0 = {0.f,0.f,0.f,0.f}, z1 = z0, z2 = z0, z3 = z0;
#pragma unroll
      for (int kc = 0; kc < 16; kc++){
        bf16x8 a0 = *(const bf16x8*)(L + H_S + lo * HSTR        + kc*64 + hi*16);
        bf16x8 a1 = *(const bf16x8*)(L + H_S + (16 + lo) * HSTR + kc*64 + hi*16);
        z0 = MFMA(a0, bP[kc], z0);
        z1 = MFMA(a1, bP[kc], z1);
        z2 = MFMA(a0, bQ[kc], z2);
        z3 = MFMA(a1, bQ[kc], z3);
      }
      int tb = wave * 4;   // tiles {0..3} = Zi m0,m1, Zf m0,m1 ; {4..7} = Zo,Zc
      zstore(L, tb+0, lane, z0); zstore(L, tb+1, lane, z1);
      zstore(L, tb+2, lane, z2); zstore(L, tb+3, lane, z3);
    } else {
      // wave2: x-projections m0 (4 gates) + decomp m0 ; wave3: same for m1
      const int m = wave - 2;
      f32x4 xi = {0.f,0.f,0.f,0.f}, xf = xi, xo = xi, xcg = xi, zd = xi;
#pragma unroll
      for (int q = 0; q < 8; q++){
        bf16x8 a  = *(const bf16x8*)(L + X_S   + (m*16 + lo) * XSTR + q*64 + hi*16);
        bf16x8 w0 = *(const bf16x8*)(L + WIN_S + (0*16 + lo) * XSTR + q*64 + hi*16);
        bf16x8 w1 = *(const bf16x8*)(L + WIN_S + (1*16 + lo) * XSTR + q*64 + hi*16);
        bf16x8 w2 = *(const bf16x8*)(L + WIN_S + (2*16 + lo) * XSTR + q*64 + hi*16);
        bf16x8 w3 = *(const bf16x8*)(L + WIN_S + (3*16 + lo) * XSTR + q*64 + hi*16);
        xi  = MFMA(a, w0, xi);  xf  = MFMA(a, w1, xf);
        xo  = MFMA(a, w2, xo);  xcg = MFMA(a, w3, xcg);
      }
#pragma unroll
      for (int kc = 0; kc < 16; kc++){
        bf16x8 a = *(const bf16x8*)(L + C_S + (m*16 + lo) * HSTR + kc*64 + hi*16);
        zd = MFMA(a, bP[kc], zd);
      }
      zstore(L, 8+4*m+0, lane, xi);  zstore(L, 8+4*m+1, lane, xf);
      zstore(L, 8+4*m+2, lane, xo);  zstore(L, 8+4*m+3, lane, xcg);
      zstore(L, 16+m,    lane, zd);
    }
    __syncthreads();

    // ---- elementwise gate math (fp32); publish tagged u64 (no drain, no flag)
    {
      const int m = erow >> 4, r16 = erow & 15;
      float Tmap = 1.f / __logf(tv + 2.7183f);
      unsigned int hpk = 0, cpk = 0;
      float hv2[2];
#pragma unroll
      for (int e = 0; e < 2; e++){
        int col = ecp + e;
        float zi = zread(L, 0*2+m, r16, col) + zread(L, 8+4*m+0, r16, col) + bias_i[e];
        float zf = zread(L, 1*2+m, r16, col) + zread(L, 8+4*m+1, r16, col) + bias_f[e];
        float zo = zread(L, 2*2+m, r16, col) + zread(L, 8+4*m+2, r16, col) + bias_o[e];
        float zc = zread(L, 3*2+m, r16, col) + zread(L, 8+4*m+3, r16, col) + bias_c[e];
        float zdv = zread(L, 16+m, r16, col) + bias_d[e];
        float cst = ftanh(zdv);
        float c1  = cr[e] - cst + Tmap * cst;
        float ig = fsigm(zi), fg = fsigm(zf), og = fsigm(zo);
        float ch = ftanh(zc);
        float c2 = fg * c1 + ig * ch;
        float hv_ = og * ftanh(c2);
        cr[e] = c2; hv2[e] = hv_;
        hpk |= (unsigned int)__builtin_bit_cast(unsigned short, (__bf16)hv_) << (16*e);
        cpk |= (unsigned int)__builtin_bit_cast(unsigned short, (__bf16)c2) << (16*e);
      }
      if (t < T_STEPS - 1){
        const unsigned int wtag  = (unsigned int)((t + 1) & 3);
        const unsigned int tmask = (wtag & 1u) | ((wtag >> 1) << 16);
        hpk = (hpk & 0xFFFEFFFEu) | tmask;   // full tag in both bf16 LSBs
        cpk = (cpk & 0xFFFEFFFEu) | tmask;
        size_t off = ((size_t)(rbase + erow) * 256 + (cbase >> 1) + (tid & 7)) * 8;
        cst8(hcnext + off,
             (unsigned long long)hpk | ((unsigned long long)cpk << 32));
      } else {
        size_t off = (size_t)(rbase + erow) * HID + cbase + ecp;
        P.h_final[off]     = hv2[0];
        P.h_final[off + 1] = hv2[1];
      }
    }
    __syncthreads();   // keep R6's iteration-tail join (cheap, safe)
  }
}

// ---------------- head: out = relu(hT @ fc_w^T + fc_b) @ cls_w^T + cls_b ----
__global__ void __launch_bounds__(256) tlstm_head(const float* __restrict__ hfin,
    const float* __restrict__ fc_w, const float* __restrict__ fc_b,
    const float* __restrict__ cls_w, const float* __restrict__ cls_b,
    float* __restrict__ out)
{
  __shared__ float hrow[512];
  __shared__ float fcv[256];
  const int b = blockIdx.x, tid = threadIdx.x;
  ((float2*)hrow)[tid] = ((const float2*)(hfin + (size_t)b * 512))[tid];
  __syncthreads();
  {
    const float4* w4 = (const float4*)(fc_w + (size_t)tid * 512);
    const float4* h4 = (const float4*)hrow;
    float acc = fc_b[tid];
#pragma unroll 4
    for (int k = 0; k < 128; k++){
      float4 w = w4[k], h = h4[k];
      acc += w.x*h.x + w.y*h.y + w.z*h.z + w.w*h.w;
    }
    fcv[tid] = fmaxf(acc, 0.f);
  }
  __syncthreads();
  const int wave = tid >> 6, lane = tid & 63;
  if (wave < 2){
    const float* cw = cls_w + wave * 256;
    float s = 0.f;
#pragma unroll
    for (int j = lane; j < 256; j += 64) s += fcv[j] * cw[j];
#pragma unroll
    for (int off = 32; off > 0; off >>= 1) s += __shfl_down(s, off, 64);
    if (lane == 0) out[b * 2 + wave] = s + cls_b[wave];
  }
}

// ---------------------------------------------------------------------------
extern "C" void kernel_launch(void* const* d_in, const int* in_sizes, int n_in,
                              void* d_out, int out_size, void* d_ws, size_t ws_size,
                              hipStream_t stream)
{
  (void)in_sizes; (void)n_in; (void)out_size; (void)ws_size;

  ScanP P;
  P.x    = (const float*)d_in[0];
  P.tim  = (const float*)d_in[1];
  P.Wi_w = (const float*)d_in[2];  P.Wi_b = (const float*)d_in[3];
  P.Ui_w = (const float*)d_in[4];  P.Ui_b = (const float*)d_in[5];  P.bi  = (const float*)d_in[6];
  P.Wf_w = (const float*)d_in[7];  P.Wf_b = (const float*)d_in[8];
  P.Uf_w = (const float*)d_in[9];  P.Uf_b = (const float*)d_in[10]; P.bf_ = (const float*)d_in[11];
  P.Wo_w = (const float*)d_in[12]; P.Wo_b = (const float*)d_in[13];
  P.Uo_w = (const float*)d_in[14]; P.Uo_b = (const float*)d_in[15]; P.bo  = (const float*)d_in[16];
  P.Wc_w = (const float*)d_in[17]; P.Wc_b = (const float*)d_in[18];
  P.Uc_w = (const float*)d_in[19]; P.Uc_b = (const float*)d_in[20]; P.bc  = (const float*)d_in[21];
  P.Wd_w = (const float*)d_in[22]; P.b_dec = (const float*)d_in[23];
  const float* fc_w  = (const float*)d_in[24];
  const float* fc_b  = (const float*)d_in[25];
  const float* cls_w = (const float*)d_in[26];
  const float* cls_b = (const float*)d_in[27];

  // workspace layout (identical to R3/R6): [hc_buf 1M][flags 1K][h_final 512K]
  unsigned long long* hc_buf = (unsigned long long*)d_ws;        // 2*256*256 u64
  unsigned int* flags = (unsigned int*)(hc_buf + 2 * BATCH * 256);
  float* h_final = (float*)((char*)flags + 1024);                // 256*512 f32
  P.hc_buf = hc_buf; P.h_final = h_final; P.flags = flags;

  const size_t zero_bytes = (size_t)2 * BATCH * 256 * 8 + 1024;  // hc + flags
  hipMemsetAsync(d_ws, 0, zero_bytes, stream);

  hipLaunchKernelGGL(tlstm_scan, dim3(256), dim3(256), 0, stream, P);
  hipLaunchKernelGGL(tlstm_head, dim3(256), dim3(256), 0, stream,
                     h_final, fc_w, fc_b, cls_w, cls_b, (float*)d_out);
}

// Round 10
// 1065.519 us; speedup vs baseline: 1.5338x; 1.0933x over previous
//
#include <hip/hip_runtime.h>

// ---------------------------------------------------------------------------
// TLSTM  (B=256, T=256, D=256, H=512)
// Persistent-scan, R9 = R8 exchange protocol (proven) + re-tiled decomposition
// to halve MALL broadcast redundancy:
//   grid = 256 WGs x 256 thr (1 WG/CU). WG (g,cs): g=bid&15 owns batch rows
//   [g*16,+16), cs=bid>>4 owns h-cols [cs*32,+32). Peer group = 16 WGs
//   (was 32); per-WG exchange read = 32KB (was 64KB); total 8MB/step (was 16).
//   4 waves: wave w (nt=w&1, p=w>>1): U-GEMM gates {2p,2p+1} at N-tile nt
//   (B-frags in regs), xproj same gates (Win in LDS), waves 2/3 also decomp
//   (Wd frags in regs). One M-tile (16 rows).
//   Exchange: tagged u64 per col-pair [h0,h1|c0,c1], 2-bit step tag in LSBs
//   of all four bf16; sc0sc1 loads/stores; validate + selective retry
//   (guarded) — R8 verbatim. 3 barriers/step (redundant top barrier removed).
// ---------------------------------------------------------------------------

#define T_STEPS 256
#define BATCH   256
#define DIN     256
#define HID     512

typedef __attribute__((ext_vector_type(8))) __bf16 bf16x8;
typedef __attribute__((ext_vector_type(4))) float  f32x4;

#define MFMA(a,b,c) __builtin_amdgcn_mfma_f32_16x16x32_bf16((a),(b),(c),0,0,0)

// LDS layout (byte offsets).
#define H_S     0            // 16 x 1040B
#define C_S     16640        // 16 x 1040B
#define X_S     33280        // 16 x 528B
#define WIN_S   41728        // 4 gates x 32 cols x 528B = 67584
#define Z_S     109312       // 18 tiles x 16x17 f32 = 19584
#define LDS_SZ  128896
#define HSTR    1040
#define XSTR    528
#define ZROW    17
// Z tile ids: U gate g at N-tile nt = g*2+nt (0..7); decomp = 8+nt;
//             xproj gate g at nt = 10+g*2+nt (10..17)

struct ScanP {
  const float *x, *tim;
  const float *Wi_w,*Wi_b,*Ui_w,*Ui_b,*bi;
  const float *Wf_w,*Wf_b,*Uf_w,*Uf_b,*bf_;
  const float *Wo_w,*Wo_b,*Uo_w,*Uo_b,*bo;
  const float *Wc_w,*Wc_b,*Uc_w,*Uc_b,*bc;
  const float *Wd_w,*b_dec;
  unsigned long long *hc_buf;      // [2][256 rows][256 col-pairs] u64
  float *h_final;                  // [256][512] fp32
  unsigned int *flags;             // kept in ws layout; unused
};

__device__ __forceinline__ float fsigm(float z){ return 1.f/(1.f + __expf(-z)); }
__device__ __forceinline__ float ftanh(float z){
  float e = __expf(-2.f*fabsf(z));
  float t = (1.f - e)/(1.f + e);
  return z < 0.f ? -t : t;
}

// device-coherent via MALL (bypass non-coherent L1+L2) — R3/R6/R8-proven path
__device__ __forceinline__ uint4 cld16(const void* p){
  uint4 r;
  asm volatile("global_load_dwordx4 %0, %1, off sc0 sc1"
               : "=v"(r) : "v"(p) : "memory");
  return r;
}
__device__ __forceinline__ void cst8(void* p, unsigned long long v){
  asm volatile("global_store_dwordx2 %0, %1, off sc0 sc1"
               :: "v"(p), "v"(v) : "memory");
}

__device__ __forceinline__ bf16x8 wfrag8(const float* p){
  const float4* p4 = (const float4*)p;
  float4 a = p4[0], b = p4[1];
  bf16x8 r = { (__bf16)a.x,(__bf16)a.y,(__bf16)a.z,(__bf16)a.w,
               (__bf16)b.x,(__bf16)b.y,(__bf16)b.z,(__bf16)b.w };
  return r;
}
__device__ __forceinline__ void zstore(char* L, int tile, int lane, f32x4 v){
  float* p = (float*)(L + Z_S) + tile*(16*ZROW) + ((lane>>4)*4)*ZROW + (lane&15);
  p[0]=v[0]; p[ZROW]=v[1]; p[2*ZROW]=v[2]; p[3*ZROW]=v[3];
}
__device__ __forceinline__ float zread(const char* L, int tile, int r, int c){
  return ((const float*)(L + Z_S))[tile*(16*ZROW) + r*ZROW + c];
}

__global__ void __launch_bounds__(256, 1) tlstm_scan(ScanP P)
{
  __shared__ __align__(16) char L[LDS_SZ];
  const int tid  = threadIdx.x;
  const int bid  = blockIdx.x;
  const int g    = bid & 15;         // row group (16 groups x 16 rows)
  const int cs   = bid >> 4;         // col slice (16 slices x 32 cols)
  const int rbase = g * 16;
  const int cbase = cs * 32;
  const int wave = tid >> 6, lane = tid & 63, lo = lane & 15, hi = lane >> 4;
  const int nt   = wave & 1;         // N-tile within the 32-col slice
  const int gp   = wave >> 1;        // gate pair: 0 -> {i,f}, 1 -> {o,c}
  const int g0   = gp * 2, g1 = g0 + 1;

  // ---- one-time: Win slices (4 gates x 32 cols x 256) fp32 -> bf16 -> LDS
  //      wave = gate; lane: wc = col (0..31), q2 = half (128 floats)
  {
    const float* Wg = (wave == 0) ? P.Wi_w : (wave == 1) ? P.Wf_w
                    : (wave == 2) ? P.Wo_w : P.Wc_w;
    const int wc = lane >> 1, q2 = lane & 1;
    const float4* src = (const float4*)(Wg + (size_t)(cbase + wc) * DIN + q2 * 128);
    char* dst = L + WIN_S + (size_t)(wave * 32 + wc) * XSTR + q2 * 256;
#pragma unroll
    for (int j = 0; j < 16; j++){
      float4 a = src[2*j], b = src[2*j+1];
      bf16x8 o = { (__bf16)a.x,(__bf16)a.y,(__bf16)a.z,(__bf16)a.w,
                   (__bf16)b.x,(__bf16)b.y,(__bf16)b.z,(__bf16)b.w };
      *(bf16x8*)(dst + j*16) = o;
    }
  }

  // ---- one-time: U/Wd B-fragments -> registers (loop-invariant)
  //      wave: gates g0,g1 at cols cbase+nt*16; waves 2/3 also Wd
  bf16x8 bP[16], bQ[16], bR[16];
  {
    const float* Pw = (gp == 0) ? P.Ui_w : P.Uo_w;
    const float* Qw = (gp == 0) ? P.Uf_w : P.Uc_w;
    const size_t colb = (size_t)(cbase + nt * 16 + lo) * HID;
#pragma unroll
    for (int kc = 0; kc < 16; kc++){
      bP[kc] = wfrag8(Pw + colb + kc * 32 + hi * 8);
      bQ[kc] = wfrag8(Qw + colb + kc * 32 + hi * 8);
    }
    if (wave >= 2){
#pragma unroll
      for (int kc = 0; kc < 16; kc++)
        bR[kc] = wfrag8(P.Wd_w + colb + kc * 32 + hi * 8);
    }
  }

  // ---- per-thread elementwise ownership: erow=tid>>4 (16 rows),
  //      cols cbase + (tid&15)*2 .. +1
  const int erow = tid >> 4;
  const int ecp  = (tid & 15) * 2;
  float bias_i[2], bias_f[2], bias_o[2], bias_c[2], bias_d[2], cr[2];
#pragma unroll
  for (int e = 0; e < 2; e++){
    int c = cbase + ecp + e;
    bias_i[e] = P.Wi_b[c] + P.bi[c]  + P.Ui_b[c];
    bias_f[e] = P.Wf_b[c] + P.bf_[c] + P.Uf_b[c];
    bias_o[e] = P.Wo_b[c] + P.bo[c]  + P.Uo_b[c];
    bias_c[e] = P.Wc_b[c] + P.bc[c]  + P.Uc_b[c];
    bias_d[e] = P.b_dec[c];
    cr[e] = 0.f;
  }

  const int srow = tid >> 4, sseg = tid & 15;   // x staging map (16x16)
  const size_t pub_off = ((size_t)(rbase + erow) * 256 + cs * 16 + (tid & 15)) * 8;

  __syncthreads();   // Win staged before first use (also joins prologue)

#pragma unroll 1
  for (int t = 0; t < T_STEPS; ++t){
    const int rp = t & 1;
    const char* hcprev = (const char*)(P.hc_buf + (size_t)rp * BATCH * 256);
    char* hcnext = (char*)(P.hc_buf + (size_t)(rp ^ 1) * BATCH * 256);

    // x slice + tim (independent of peers): issue early (plain cached loads)
    const float4* xsrc = (const float4*)(P.x + ((size_t)(rbase + srow) * T_STEPS + t) * DIN + sseg * 16);
    float4 xv[4];
#pragma unroll
    for (int j = 0; j < 4; j++) xv[j] = xsrc[j];
    float tv = P.tim[(size_t)(rbase + erow) * T_STEPS + t];

    // ---- issue all h/c coherent loads (8 x dwordx4 per thread, in flight)
    uint4 gr[8];
    const char* src = hcprev + (size_t)(rbase + wave * 4) * 2048;
#pragma unroll
    for (int j = 0; j < 8; j++){
      int row = j >> 1;                       // within this wave's 4 rows
      int gg  = (j & 1) * 64 + lane;          // 16B granule within row
      gr[j] = cld16(src + (size_t)row * 2048 + (size_t)gg * 16);
    }

    // ---- stage x (fp32 -> bf16) — fills the h/c load shadow
    {
      char* dst = L + X_S + srow * XSTR + sseg * 32;
#pragma unroll
      for (int j = 0; j < 2; j++){
        float4 a = xv[2*j], b = xv[2*j+1];
        bf16x8 o = { (__bf16)a.x,(__bf16)a.y,(__bf16)a.z,(__bf16)a.w,
                     (__bf16)b.x,(__bf16)b.y,(__bf16)b.z,(__bf16)b.w };
        *(bf16x8*)(dst + j*16) = o;
      }
    }

    asm volatile("s_waitcnt vmcnt(0)" ::: "memory");
    __builtin_amdgcn_sched_barrier(0);

    // ---- validate tags; selective retry (R8 verbatim, 8 entries)
    {
      const unsigned int expv = (unsigned int)(t & 1)
                              | ((unsigned int)((t >> 1) & 1) << 16);
      unsigned int stale = 0;
#pragma unroll
      for (int j = 0; j < 8; j++){
        unsigned int bad = ((gr[j].x ^ expv) | (gr[j].y ^ expv)
                          | (gr[j].z ^ expv) | (gr[j].w ^ expv)) & 0x00010001u;
        stale |= (bad ? 1u : 0u) << j;
      }
      int guard = 0;
      while (__any((int)stale) && ++guard < 65536){
#pragma unroll
        for (int j = 0; j < 8; j++){
          if (stale & (1u << j)){
            int row = j >> 1;
            int gg  = (j & 1) * 64 + lane;
            gr[j] = cld16(src + (size_t)row * 2048 + (size_t)gg * 16);
          }
        }
        asm volatile("s_waitcnt vmcnt(0)" ::: "memory");
        __builtin_amdgcn_sched_barrier(0);
        unsigned int ns = 0;
#pragma unroll
        for (int j = 0; j < 8; j++){
          if (stale & (1u << j)){
            unsigned int bad = ((gr[j].x ^ expv) | (gr[j].y ^ expv)
                              | (gr[j].z ^ expv) | (gr[j].w ^ expv)) & 0x00010001u;
            ns |= (bad ? 1u : 0u) << j;
          }
        }
        stale = ns;
      }
    }

    // ---- commit h/c to LDS. gr = [h01,c01,h23,c23] -> h {x,z}, c {y,w}
    {
#pragma unroll
      for (int j = 0; j < 8; j++){
        int row = wave * 4 + (j >> 1);
        int gg  = (j & 1) * 64 + lane;
        *(uint2*)(L + H_S + row * HSTR + gg * 8) = uint2{gr[j].x, gr[j].z};
        *(uint2*)(L + C_S + row * HSTR + gg * 8) = uint2{gr[j].y, gr[j].w};
      }
    }
    __syncthreads();

    // ---- MFMA phase (single M-tile; all waves read same A-frags: broadcast)
    {
      f32x4 zA = {0.f,0.f,0.f,0.f}, zB = zA, zD = zA, xA = zA, xB = zA;
#pragma unroll
      for (int kc = 0; kc < 16; kc++){
        bf16x8 a = *(const bf16x8*)(L + H_S + lo * HSTR + kc*64 + hi*16);
        zA = MFMA(a, bP[kc], zA);
        zB = MFMA(a, bQ[kc], zB);
      }
      if (wave >= 2){
#pragma unroll
        for (int kc = 0; kc < 16; kc++){
          bf16x8 a = *(const bf16x8*)(L + C_S + lo * HSTR + kc*64 + hi*16);
          zD = MFMA(a, bR[kc], zD);
        }
      }
#pragma unroll
      for (int q = 0; q < 8; q++){
        bf16x8 ax = *(const bf16x8*)(L + X_S + lo * XSTR + q*64 + hi*16);
        bf16x8 w0 = *(const bf16x8*)(L + WIN_S + (size_t)(g0*32 + nt*16 + lo) * XSTR + q*64 + hi*16);
        bf16x8 w1 = *(const bf16x8*)(L + WIN_S + (size_t)(g1*32 + nt*16 + lo) * XSTR + q*64 + hi*16);
        xA = MFMA(ax, w0, xA);
        xB = MFMA(ax, w1, xB);
      }
      zstore(L, g0*2+nt,    lane, zA);  zstore(L, g1*2+nt,    lane, zB);
      zstore(L, 10+g0*2+nt, lane, xA);  zstore(L, 10+g1*2+nt, lane, xB);
      if (wave >= 2) zstore(L, 8+nt, lane, zD);
    }
    __syncthreads();

    // ---- elementwise gate math (fp32); publish tagged u64
    {
      float Tmap = 1.f / __logf(tv + 2.7183f);
      unsigned int hpk = 0, cpk = 0;
      float hv2[2];
#pragma unroll
      for (int e = 0; e < 2; e++){
        int col = ecp + e;
        int ntc = col >> 4, cl = col & 15;
        float zi = zread(L, 0+ntc,  erow, cl) + zread(L, 10+0+ntc,  erow, cl) + bias_i[e];
        float zf = zread(L, 2+ntc,  erow, cl) + zread(L, 10+2+ntc,  erow, cl) + bias_f[e];
        float zo = zread(L, 4+ntc,  erow, cl) + zread(L, 10+4+ntc,  erow, cl) + bias_o[e];
        float zc = zread(L, 6+ntc,  erow, cl) + zread(L, 10+6+ntc,  erow, cl) + bias_c[e];
        float zdv = zread(L, 8+ntc, erow, cl) + bias_d[e];
        float cst = ftanh(zdv);
        float c1  = cr[e] - cst + Tmap * cst;
        float ig = fsigm(zi), fg = fsigm(zf), og = fsigm(zo);
        float ch = ftanh(zc);
        float c2 = fg * c1 + ig * ch;
        float hv_ = og * ftanh(c2);
        cr[e] = c2; hv2[e] = hv_;
        hpk |= (unsigned int)__builtin_bit_cast(unsigned short, (__bf16)hv_) << (16*e);
        cpk |= (unsigned int)__builtin_bit_cast(unsigned short, (__bf16)c2) << (16*e);
      }
      if (t < T_STEPS - 1){
        const unsigned int wtag  = (unsigned int)((t + 1) & 3);
        const unsigned int tmask = (wtag & 1u) | ((wtag >> 1) << 16);
        hpk = (hpk & 0xFFFEFFFEu) | tmask;   // full tag in both bf16 LSBs
        cpk = (cpk & 0xFFFEFFFEu) | tmask;
        cst8(hcnext + pub_off,
             (unsigned long long)hpk | ((unsigned long long)cpk << 32));
      } else {
        size_t off = (size_t)(rbase + erow) * HID + cbase + ecp;
        P.h_final[off]     = hv2[0];
        P.h_final[off + 1] = hv2[1];
      }
    }
    __syncthreads();   // tail join: Z reads done before next step's writes
  }
}

// ---------------- head: out = relu(hT @ fc_w^T + fc_b) @ cls_w^T + cls_b ----
__global__ void __launch_bounds__(256) tlstm_head(const float* __restrict__ hfin,
    const float* __restrict__ fc_w, const float* __restrict__ fc_b,
    const float* __restrict__ cls_w, const float* __restrict__ cls_b,
    float* __restrict__ out)
{
  __shared__ float hrow[512];
  __shared__ float fcv[256];
  const int b = blockIdx.x, tid = threadIdx.x;
  ((float2*)hrow)[tid] = ((const float2*)(hfin + (size_t)b * 512))[tid];
  __syncthreads();
  {
    const float4* w4 = (const float4*)(fc_w + (size_t)tid * 512);
    const float4* h4 = (const float4*)hrow;
    float acc = fc_b[tid];
#pragma unroll 4
    for (int k = 0; k < 128; k++){
      float4 w = w4[k], h = h4[k];
      acc += w.x*h.x + w.y*h.y + w.z*h.z + w.w*h.w;
    }
    fcv[tid] = fmaxf(acc, 0.f);
  }
  __syncthreads();
  const int wave = tid >> 6, lane = tid & 63;
  if (wave < 2){
    const float* cw = cls_w + wave * 256;
    float s = 0.f;
#pragma unroll
    for (int j = lane; j < 256; j += 64) s += fcv[j] * cw[j];
#pragma unroll
    for (int off = 32; off > 0; off >>= 1) s += __shfl_down(s, off, 64);
    if (lane == 0) out[b * 2 + wave] = s + cls_b[wave];
  }
}

// ---------------------------------------------------------------------------
extern "C" void kernel_launch(void* const* d_in, const int* in_sizes, int n_in,
                              void* d_out, int out_size, void* d_ws, size_t ws_size,
                              hipStream_t stream)
{
  (void)in_sizes; (void)n_in; (void)out_size; (void)ws_size;

  ScanP P;
  P.x    = (const float*)d_in[0];
  P.tim  = (const float*)d_in[1];
  P.Wi_w = (const float*)d_in[2];  P.Wi_b = (const float*)d_in[3];
  P.Ui_w = (const float*)d_in[4];  P.Ui_b = (const float*)d_in[5];  P.bi  = (const float*)d_in[6];
  P.Wf_w = (const float*)d_in[7];  P.Wf_b = (const float*)d_in[8];
  P.Uf_w = (const float*)d_in[9];  P.Uf_b = (const float*)d_in[10]; P.bf_ = (const float*)d_in[11];
  P.Wo_w = (const float*)d_in[12]; P.Wo_b = (const float*)d_in[13];
  P.Uo_w = (const float*)d_in[14]; P.Uo_b = (const float*)d_in[15]; P.bo  = (const float*)d_in[16];
  P.Wc_w = (const float*)d_in[17]; P.Wc_b = (const float*)d_in[18];
  P.Uc_w = (const float*)d_in[19]; P.Uc_b = (const float*)d_in[20]; P.bc  = (const float*)d_in[21];
  P.Wd_w = (const float*)d_in[22]; P.b_dec = (const float*)d_in[23];
  const float* fc_w  = (const float*)d_in[24];
  const float* fc_b  = (const float*)d_in[25];
  const float* cls_w = (const float*)d_in[26];
  const float* cls_b = (const float*)d_in[27];

  // workspace layout (identical to R3/R6/R8): [hc_buf 1M][flags 1K][h_final 512K]
  unsigned long long* hc_buf = (unsigned long long*)d_ws;        // 2*256*256 u64
  unsigned int* flags = (unsigned int*)(hc_buf + 2 * BATCH * 256);
  float* h_final = (float*)((char*)flags + 1024);                // 256*512 f32
  P.hc_buf = hc_buf; P.h_final = h_final; P.flags = flags;

  const size_t zero_bytes = (size_t)2 * BATCH * 256 * 8 + 1024;  // hc + flags
  hipMemsetAsync(d_ws, 0, zero_bytes, stream);

  hipLaunchKernelGGL(tlstm_scan, dim3(256), dim3(256), 0, stream, P);
  hipLaunchKernelGGL(tlstm_head, dim3(256), dim3(256), 0, stream,
                     h_final, fc_w, fc_b, cls_w, cls_b, (float*)d_out);
}